// Round 5
// baseline (808.110 us; speedup 1.0000x reference)
//
#include <hip/hip_runtime.h>

#define H 128

struct NetParams { const float *Win, *bi, *Wh, *bh, *Wout, *bo; };

// ---------------- tanh jet composition (Faa di Bruno) ----------------
// JET=5 : [u, ux, uxx, uy, uyy]          (two independent directional 2-jets)
// JET=10: [u, ux, uy, uxx, uxy, uyy, uxxx, uxxy, uxyy, uyyy]
template<int JET>
__device__ inline void tanh_jet(const float* z, float* o) {
  float t  = tanhf(z[0]);
  float t1 = 1.0f - t * t;          // t'
  o[0] = t;
  if constexpr (JET >= 5) {
    float t2 = -2.0f * t * t1;      // t''
    if constexpr (JET == 5) {
      o[1] = t1 * z[1];
      o[2] = t2 * z[1] * z[1] + t1 * z[2];
      o[3] = t1 * z[3];
      o[4] = t2 * z[3] * z[3] + t1 * z[4];
    } else { // JET == 10
      float t3 = t1 * (6.0f * t * t - 2.0f);   // t'''
      float zx = z[1], zy = z[2], zxx = z[3], zxy = z[4], zyy = z[5];
      o[1] = t1 * zx;
      o[2] = t1 * zy;
      o[3] = t2 * zx * zx + t1 * zxx;
      o[4] = t2 * zx * zy + t1 * zxy;
      o[5] = t2 * zy * zy + t1 * zyy;
      o[6] = t3 * zx * zx * zx + 3.0f * t2 * zx * zxx + t1 * z[6];
      o[7] = t3 * zx * zx * zy + t2 * (zxx * zy + 2.0f * zxy * zx) + t1 * z[7];
      o[8] = t3 * zx * zy * zy + t2 * (zyy * zx + 2.0f * zxy * zy) + t1 * z[8];
      o[9] = t3 * zy * zy * zy + 3.0f * t2 * zy * zyy + t1 * z[9];
    }
  }
}

// ---------------- LDS jet storage (aligned split regions) ----------------
template<int JET, int PTS>
__device__ inline void x_read(const float* X, int k, int p, float* v) {
  int idx = k * PTS + p;
  if constexpr (JET == 5) {
    float4 a = ((const float4*)X)[idx];
    v[0] = a.x; v[1] = a.y; v[2] = a.z; v[3] = a.w;
    v[4] = (X + H * PTS * 4)[idx];
  } else {
    float4 a = ((const float4*)X)[idx];
    float4 b = ((const float4*)(X + H * PTS * 4))[idx];
    float2 c = ((const float2*)(X + H * PTS * 8))[idx];
    v[0] = a.x; v[1] = a.y; v[2] = a.z; v[3] = a.w;
    v[4] = b.x; v[5] = b.y; v[6] = b.z; v[7] = b.w;
    v[8] = c.x; v[9] = c.y;
  }
}

template<int JET, int PTS>
__device__ inline void x_write(float* X, int k, int p, const float* v) {
  int idx = k * PTS + p;
  if constexpr (JET == 5) {
    ((float4*)X)[idx] = make_float4(v[0], v[1], v[2], v[3]);
    (X + H * PTS * 4)[idx] = v[4];
  } else {
    ((float4*)X)[idx] = make_float4(v[0], v[1], v[2], v[3]);
    ((float4*)(X + H * PTS * 4))[idx] = make_float4(v[4], v[5], v[6], v[7]);
    ((float2*)(X + H * PTS * 8))[idx] = make_float2(v[8], v[9]);
  }
}

// ---------------- full network jet evaluation ----------------
// Block: PTS points, 16 j-groups of 8 output neurons each. threads = PTS*16.
// Weights read directly from global (L2-resident). Hidden-layer k-loop is
// 4-deep software-pipelined with NAMED slots (rule #20: no runtime-indexed
// register arrays); loads are issued 3 load-groups ahead of their FMA pack.
// Requires the raised VGPR budget from __launch_bounds__(.,3) to survive.
template<int JET, int PTS>
__device__ void eval_net(const NetParams& P, float x, float y,
                         float* ldsX, float* ldsR, float* U) {
  const int t = threadIdx.x;
  const int p = t % PTS;
  const int g = t / PTS;

  // ---- input layer: z = x*Win[0][j] + y*Win[1][j] + bi[j]
  {
    const float4* Wi0 = (const float4*)(P.Win);
    const float4* Wi1 = (const float4*)(P.Win + H);
    const float4* Bi  = (const float4*)(P.bi);
    float4 a0 = Wi0[g * 2], a1 = Wi0[g * 2 + 1];
    float4 b0 = Wi1[g * 2], b1 = Wi1[g * 2 + 1];
    float4 c0 = Bi[g * 2],  c1 = Bi[g * 2 + 1];
    float w0v[8] = {a0.x, a0.y, a0.z, a0.w, a1.x, a1.y, a1.z, a1.w};
    float w1v[8] = {b0.x, b0.y, b0.z, b0.w, b1.x, b1.y, b1.z, b1.w};
    float bv[8]  = {c0.x, c0.y, c0.z, c0.w, c1.x, c1.y, c1.z, c1.w};
#pragma unroll
    for (int jj = 0; jj < 8; jj++) {
      float z[JET];
#pragma unroll
      for (int q = 0; q < JET; q++) z[q] = 0.0f;
      z[0] = x * w0v[jj] + y * w1v[jj] + bv[jj];
      if constexpr (JET == 5)  { z[1] = w0v[jj]; z[3] = w1v[jj]; }
      if constexpr (JET == 10) { z[1] = w0v[jj]; z[2] = w1v[jj]; }
      float o[JET];
      tanh_jet<JET>(z, o);
      x_write<JET, PTS>(ldsX, g * 8 + jj, p, o);
    }
  }
  __syncthreads();

  // ---- 3 hidden layers: 4-deep software-pipelined pass over k
  for (int l = 0; l < 3; l++) {
    const float4* Wg4 = (const float4*)(P.Wh + l * H * H) + g * 2;
    float acc[8][JET];
#pragma unroll
    for (int jj = 0; jj < 8; jj++)
#pragma unroll
      for (int q = 0; q < JET; q++) acc[jj][q] = 0.0f;

    float4 wa0, wb0, wa1, wb1, wa2, wb2, wa3, wb3;
    float xv0[JET], xv1[JET], xv2[JET], xv3[JET];

#define LOADS(WA, WB, XV, k)                                               \
    { WA = Wg4[(k) * 32]; WB = Wg4[(k) * 32 + 1];                          \
      x_read<JET, PTS>(ldsX, (k), p, XV); }
#define FMAS(WA, WB, XV)                                                   \
    { float wv[8] = {WA.x, WA.y, WA.z, WA.w, WB.x, WB.y, WB.z, WB.w};      \
      _Pragma("unroll")                                                    \
      for (int jj = 0; jj < 8; jj++)                                       \
        _Pragma("unroll")                                                  \
        for (int q = 0; q < JET; q++)                                      \
          acc[jj][q] = fmaf(wv[jj], XV[q], acc[jj][q]); }

    // prologue: slots 0..2 hold k=0..2
    LOADS(wa0, wb0, xv0, 0);
    LOADS(wa1, wb1, xv1, 1);
    LOADS(wa2, wb2, xv2, 2);

    for (int kk = 0; kk < H; kk += 4) {
      // invariant at loop top: slot0=kk, slot1=kk+1, slot2=kk+2
      LOADS(wa3, wb3, xv3, kk + 3);             FMAS(wa0, wb0, xv0);
      LOADS(wa0, wb0, xv0, (kk + 4) & (H - 1)); FMAS(wa1, wb1, xv1);
      LOADS(wa1, wb1, xv1, (kk + 5) & (H - 1)); FMAS(wa2, wb2, xv2);
      LOADS(wa2, wb2, xv2, (kk + 6) & (H - 1)); FMAS(wa3, wb3, xv3);
      // tail wrap-loads (&127) are never consumed — loop exits first
    }
#undef LOADS
#undef FMAS

    __syncthreads();  // all ldsX reads done before in-place overwrite
    const float* bhl = P.bh + l * H;
#pragma unroll
    for (int jj = 0; jj < 8; jj++) {
      float z[JET];
#pragma unroll
      for (int q = 0; q < JET; q++) z[q] = acc[jj][q];
      z[0] += bhl[g * 8 + jj];
      float o[JET];
      tanh_jet<JET>(z, o);
      x_write<JET, PTS>(ldsX, g * 8 + jj, p, o);
    }
    __syncthreads();
  }

  // ---- output layer: u = sum_k h[k] * Wout[k] + bo
  {
    float pacc[JET];
#pragma unroll
    for (int q = 0; q < JET; q++) pacc[q] = 0.0f;
    const float4* Wo = (const float4*)P.Wout;
    float4 wa = Wo[g * 2], wb = Wo[g * 2 + 1];
    float wv[8] = {wa.x, wa.y, wa.z, wa.w, wb.x, wb.y, wb.z, wb.w};
#pragma unroll
    for (int kk = 0; kk < 8; kk++) {
      float xv[JET];
      x_read<JET, PTS>(ldsX, g * 8 + kk, p, xv);
#pragma unroll
      for (int q = 0; q < JET; q++) pacc[q] = fmaf(wv[kk], xv[q], pacc[q]);
    }
#pragma unroll
    for (int q = 0; q < JET; q++) ldsR[(g * PTS + p) * JET + q] = pacc[q];
    __syncthreads();
    if (t < PTS * JET) {
      int pp = t % PTS, q = t / PTS;
      float s = 0.0f;
#pragma unroll
      for (int gg = 0; gg < 16; gg++) s += ldsR[(gg * PTS + pp) * JET + q];
      if (q == 0) s += P.bo[0];
      U[pp * JET + q] = s;
    }
    __syncthreads();
  }
}

// ---------------- kernels ----------------
// ws layout (floats): [0,2048) res1 | [2048,4096) res2 | [4096,4352) bnd1 |
// [4352,4608) bnd2 | [4608, 4608+9*512) interface terms (term-major).
#define WS_RES1 0
#define WS_RES2 2048
#define WS_BND1 4096
#define WS_BND2 4352
#define WS_INTF 4608

// LDS 46.6KB -> 3 blocks/CU; declare exactly 3 waves/EU so the register
// allocator gets the ~170-VGPR budget the 4-deep pipeline needs.
__global__ void __launch_bounds__(256, 3) residual_kernel(
    const float* xf1, const float* yf1, const float* ff1,
    const float* xf2, const float* yf2, const float* ff2,
    NetParams P1, NetParams P2, float* ws) {
  constexpr int JET = 5, PTS = 16;
  __shared__ __align__(16) float ldsX[H * PTS * JET];
  __shared__ __align__(16) float ldsR[16 * PTS * JET];
  __shared__ float U[PTS * JET];
  __shared__ float T[PTS];
  const int t = threadIdx.x;
  const int p = t % PTS;
  const int net = blockIdx.y;
  const float* xs = net ? xf2 : xf1;
  const float* ys = net ? yf2 : yf1;
  const float* fs = net ? ff2 : ff1;
  NetParams P = net ? P2 : P1;
  const int base = blockIdx.x * PTS;
  float x = xs[base + p], y = ys[base + p];
  eval_net<JET, PTS>(P, x, y, ldsX, ldsR, U);
  if (t < PTS) {
    float f = U[t * JET + 2] + U[t * JET + 4] - fs[base + t];  // uxx+uyy-ff
    T[t] = f * f;
  }
  __syncthreads();
  if (t == 0) {
    float s = 0.0f;
#pragma unroll
    for (int i = 0; i < PTS; i++) s += T[i];
    ws[(net ? WS_RES2 : WS_RES1) + blockIdx.x] = s;
  }
}

// Boundary reuses the eval_net<5,16> instantiation (JET=1 instantiation had
// a pathological codegen: 256 VGPR + scratch spill). Derivative lanes are
// computed and discarded.
__global__ void __launch_bounds__(256, 3) boundary_kernel(
    const float* xb1, const float* yb1, const float* ub1,
    const float* xb2, const float* yb2, const float* ub2,
    NetParams P1, NetParams P2, float* ws) {
  constexpr int JET = 5, PTS = 16;
  __shared__ __align__(16) float ldsX[H * PTS * JET];
  __shared__ __align__(16) float ldsR[16 * PTS * JET];
  __shared__ float U[PTS * JET];
  __shared__ float T[PTS];
  const int t = threadIdx.x;
  const int p = t % PTS;
  const int net = blockIdx.y;
  const float* xs = net ? xb2 : xb1;
  const float* ys = net ? yb2 : yb1;
  const float* us = net ? ub2 : ub1;
  NetParams P = net ? P2 : P1;
  const int base = blockIdx.x * PTS;
  float x = xs[base + p], y = ys[base + p];
  eval_net<JET, PTS>(P, x, y, ldsX, ldsR, U);
  if (t < PTS) {
    float d = us[base + t] - U[t * JET];   // value lane only
    T[t] = d * d;
  }
  __syncthreads();
  if (t == 0) {
    float s = 0.0f;
#pragma unroll
    for (int i = 0; i < PTS; i++) s += T[i];
    ws[(net ? WS_BND2 : WS_BND1) + blockIdx.x] = s;
  }
}

__global__ void __launch_bounds__(128, 2) interface_kernel(
    const float* xi, const float* yi, const float* fi,
    NetParams P1, NetParams P2, float* ws) {
  constexpr int JET = 10, PTS = 8;
  __shared__ __align__(16) float ldsX[H * PTS * JET];
  __shared__ __align__(16) float ldsR[16 * PTS * JET];
  __shared__ float U1[PTS * JET];
  __shared__ float U2[PTS * JET];
  __shared__ float T[PTS * 9];
  const int t = threadIdx.x;
  const int p = t % PTS;
  const int base = blockIdx.x * PTS;
  float x = xi[base + p], y = yi[base + p];
  eval_net<JET, PTS>(P1, x, y, ldsX, ldsR, U1);
  eval_net<JET, PTS>(P2, x, y, ldsX, ldsR, U2);
  if (t < PTS) {
    const float* a = U1 + t * JET;
    const float* b = U2 + t * JET;
    float fsrc = fi[base + t];
    float f1 = a[3] + a[5] - fsrc;           // v1xx+v1yy-fi
    float f2 = b[3] + b[5] - fsrc;
    float du = a[0] - b[0];
    float fd = f1 - f2;
    float dfl = a[2] - b[2];                 // v1y - v2y
    float g1x = a[6] + a[8], g1y = a[7] + a[9];
    float g2x = b[6] + b[8], g2y = b[7] + b[9];
    float dyy = a[5] - b[5];
    float dx  = a[1] - b[1];
    float dxx = a[3] - b[3];
    T[t * 9 + 0] = du * du;
    T[t * 9 + 1] = f1 * f1;
    T[t * 9 + 2] = f2 * f2;
    T[t * 9 + 3] = fd * fd;
    T[t * 9 + 4] = dfl * dfl;
    T[t * 9 + 5] = g1x * g1x + g1y * g1y + g2x * g2x + g2y * g2y;
    T[t * 9 + 6] = dyy * dyy;
    T[t * 9 + 7] = dx * dx;
    T[t * 9 + 8] = dxx * dxx;
  }
  __syncthreads();
  if (t < 9) {
    float s = 0.0f;
#pragma unroll
    for (int i = 0; i < PTS; i++) s += T[i * 9 + t];
    ws[WS_INTF + t * 512 + blockIdx.x] = s;
  }
}

__global__ void __launch_bounds__(256) combine_kernel(
    const float* ws, const float* iw, float* out) {
  __shared__ float red[256];
  __shared__ float sums[13];
  const int t = threadIdx.x;
  const int off[13] = {WS_RES1, WS_RES2, WS_BND1, WS_BND2,
                       WS_INTF + 0 * 512, WS_INTF + 1 * 512, WS_INTF + 2 * 512,
                       WS_INTF + 3 * 512, WS_INTF + 4 * 512, WS_INTF + 5 * 512,
                       WS_INTF + 6 * 512, WS_INTF + 7 * 512, WS_INTF + 8 * 512};
  const int len[13] = {2048, 2048, 256, 256, 512, 512, 512, 512, 512, 512, 512, 512, 512};
  for (int r = 0; r < 13; r++) {
    float s = 0.0f;
    for (int i = t; i < len[r]; i += 256) s += ws[off[r] + i];
    red[t] = s;
    __syncthreads();
    for (int w = 128; w > 0; w >>= 1) {
      if (t < w) red[t] += red[t + w];
      __syncthreads();
    }
    if (t == 0) sums[r] = red[0];
    __syncthreads();
  }
  if (t == 0) {
    const float Nf = 32768.0f, Nb = 4096.0f, Ni = 4096.0f;
    float mse_f  = (sums[0] + sums[1]) / Nf;
    float mse_ub = (sums[2] + sums[3]) / Nb;
    float su = sums[4];
    float mse_i_u    = su / Ni;
    float mse_i_uavg = su / (2.0f * Ni);
    float mse_i_res  = (sums[5] + sums[6]) / Ni;
    float mse_cont   = sums[7] / Ni;
    float mse_flux   = sums[8] / Ni;
    float mse_gres   = sums[9] / Ni;
    float mse_uyy    = sums[10] / Ni;
    float mse_ux     = sums[11] / Ni;
    float mse_uxx    = sums[12] / Ni;
    float il = iw[0] * mse_i_u + iw[1] * mse_i_uavg + iw[2] * mse_i_res
             + iw[3] * mse_cont + iw[4] * mse_flux + iw[6] * mse_gres
             + iw[5] * mse_uyy + iw[7] * mse_ux + iw[8] * mse_uxx;
    out[0] = 20.0f * mse_ub + mse_f + 5.0f * il;
  }
}

extern "C" void kernel_launch(void* const* d_in, const int* in_sizes, int n_in,
                              void* d_out, int out_size, void* d_ws, size_t ws_size,
                              hipStream_t stream) {
  const float* xb1 = (const float*)d_in[0];
  const float* yb1 = (const float*)d_in[1];
  const float* ub1 = (const float*)d_in[2];
  const float* xb2 = (const float*)d_in[3];
  const float* yb2 = (const float*)d_in[4];
  const float* ub2 = (const float*)d_in[5];
  const float* xf1 = (const float*)d_in[6];
  const float* yf1 = (const float*)d_in[7];
  const float* ff1 = (const float*)d_in[8];
  const float* xf2 = (const float*)d_in[9];
  const float* yf2 = (const float*)d_in[10];
  const float* ff2 = (const float*)d_in[11];
  const float* xi1 = (const float*)d_in[12];
  const float* yi1 = (const float*)d_in[13];
  const float* fi1 = (const float*)d_in[14];
  const float* iw  = (const float*)d_in[15];
  NetParams P1 = {(const float*)d_in[16], (const float*)d_in[17],
                  (const float*)d_in[18], (const float*)d_in[19],
                  (const float*)d_in[20], (const float*)d_in[21]};
  NetParams P2 = {(const float*)d_in[22], (const float*)d_in[23],
                  (const float*)d_in[24], (const float*)d_in[25],
                  (const float*)d_in[26], (const float*)d_in[27]};
  float* ws = (float*)d_ws;
  float* out = (float*)d_out;

  dim3 gridR(2048, 2);
  hipLaunchKernelGGL(residual_kernel, gridR, dim3(256), 0, stream,
                     xf1, yf1, ff1, xf2, yf2, ff2, P1, P2, ws);
  dim3 gridB(256, 2);
  hipLaunchKernelGGL(boundary_kernel, gridB, dim3(256), 0, stream,
                     xb1, yb1, ub1, xb2, yb2, ub2, P1, P2, ws);
  hipLaunchKernelGGL(interface_kernel, dim3(512), dim3(128), 0, stream,
                     xi1, yi1, fi1, P1, P2, ws);
  hipLaunchKernelGGL(combine_kernel, dim3(1), dim3(256), 0, stream,
                     ws, iw, out);
}

// Round 6
// 451.619 us; speedup vs baseline: 1.7894x; 1.7894x over previous
//
#include <hip/hip_runtime.h>

#define H 128

typedef __attribute__((ext_vector_type(4))) float f32x4;
typedef __attribute__((ext_vector_type(8))) short short8;

struct NetParams { const float *Win, *bi, *Wh, *bh, *Wout, *bo; };

// ---------------- bf16 split helpers ----------------
__device__ inline unsigned short f2bf(float f) {
  unsigned u = __float_as_uint(f);
  unsigned r = (u + 0x7FFFu + ((u >> 16) & 1u)) >> 16;   // RNE
  return (unsigned short)r;
}
__device__ inline float bf2f(unsigned short h) {
  return __uint_as_float(((unsigned)h) << 16);
}
__device__ inline void split_bf(float x, unsigned short& hi, unsigned short& lo) {
  hi = f2bf(x);
  lo = f2bf(x - bf2f(hi));
}

// ---------------- tanh jet composition (Faa di Bruno) ----------------
// JET=5 : [u, ux, uxx, uy, uyy]
// JET=10: [u, ux, uy, uxx, uxy, uyy, uxxx, uxxy, uxyy, uyyy]
template<int JET>
__device__ inline void tanh_jet(const float* z, float* o) {
  float t  = tanhf(z[0]);
  float t1 = 1.0f - t * t;
  o[0] = t;
  float t2 = -2.0f * t * t1;
  if constexpr (JET == 5) {
    o[1] = t1 * z[1];
    o[2] = t2 * z[1] * z[1] + t1 * z[2];
    o[3] = t1 * z[3];
    o[4] = t2 * z[3] * z[3] + t1 * z[4];
  } else { // JET == 10
    float t3 = t1 * (6.0f * t * t - 2.0f);
    float zx = z[1], zy = z[2], zxx = z[3], zxy = z[4], zyy = z[5];
    o[1] = t1 * zx;
    o[2] = t1 * zy;
    o[3] = t2 * zx * zx + t1 * zxx;
    o[4] = t2 * zx * zy + t1 * zxy;
    o[5] = t2 * zy * zy + t1 * zyy;
    o[6] = t3 * zx * zx * zx + 3.0f * t2 * zx * zxx + t1 * z[6];
    o[7] = t3 * zx * zx * zy + t2 * (zxx * zy + 2.0f * zxy * zx) + t1 * z[7];
    o[8] = t3 * zx * zy * zy + t2 * (zyy * zx + 2.0f * zxy * zy) + t1 * z[8];
    o[9] = t3 * zy * zy * zy + 3.0f * t2 * zy * zyy + t1 * z[9];
  }
}

// X LDS layout [64 cols][128 k] ushort, XOR-swizzled at 8-ushort granularity
// (kb ^= n&7) so a 16-lane MFMA B-frag read spreads across banks (T2).
__device__ inline int xpos(int n, int k) {
  return n * H + (((k >> 3) ^ (n & 7)) << 3) + (k & 7);
}

// ---------------- MFMA network jet evaluation ----------------
// Block = 256 threads (4 waves). NCOL = NPTS*JETP = 64 GEMM columns.
// Per hidden layer: per wave 2 M-tiles (rows wv*32..+31) x 4 N-tiles x
// K=128 (4 K-steps) x 3 split-MFMAs. A-frags (W^T hi/lo) held in regs for
// the whole layer; B-frags from swizzled LDS; D bounced via Z[16][132] f32
// scratch for the cross-lane tanh-jet pass.
template<int JET, int JETP, int NPTS>
__device__ void eval_mfma(const float* xs, const float* ys, int base,
                          const NetParams& P,
                          const unsigned short* wth, const unsigned short* wtl,
                          unsigned short* Xh, unsigned short* Xl,
                          float* Zf, float* U) {
  constexpr int NCOL = NPTS * JETP;  // 64
  const int t = threadIdx.x;

  // ---- input layer: 2 -> H, jets seeded from Win directions
#pragma unroll
  for (int i = 0; i < NPTS * H / 256; i++) {
    int pair = t + i * 256;
    int p = pair >> 7, j = pair & (H - 1);
    float w0 = P.Win[j], w1 = P.Win[H + j], b = P.bi[j];
    float xp = xs[base + p], yp = ys[base + p];
    float z[JET];
#pragma unroll
    for (int q = 0; q < JET; q++) z[q] = 0.0f;
    z[0] = xp * w0 + yp * w1 + b;
    if constexpr (JET == 5) { z[1] = w0; z[3] = w1; }
    else                    { z[1] = w0; z[2] = w1; }
    float o[JET];
    tanh_jet<JET>(z, o);
#pragma unroll
    for (int q = 0; q < JET; q++) {
      unsigned short hi, lo; split_bf(o[q], hi, lo);
      int pos = xpos(p * JETP + q, j);
      Xh[pos] = hi; Xl[pos] = lo;
    }
  }
  __syncthreads();

  const int lane = t & 63, wv = t >> 6;
  const int jl = lane & 15, kg = lane >> 4;

  // ---- 3 hidden layers
  for (int l = 0; l < 3; l++) {
    const unsigned short* Wlh = wth + l * H * H;
    const unsigned short* Wll = wtl + l * H * H;
    short8 Ah0[4], Al0[4], Ah1[4], Al1[4];   // [ks], static-indexed
#pragma unroll
    for (int ks = 0; ks < 4; ks++) {
      int koff = ks * 32 + kg * 8;
      int j0 = wv * 32 + jl;
      Ah0[ks] = *(const short8*)(Wlh + j0 * H + koff);
      Al0[ks] = *(const short8*)(Wll + j0 * H + koff);
      Ah1[ks] = *(const short8*)(Wlh + (j0 + 16) * H + koff);
      Al1[ks] = *(const short8*)(Wll + (j0 + 16) * H + koff);
    }
    for (int nt = 0; nt < 4; nt++) {
      f32x4 acc0 = {0.f, 0.f, 0.f, 0.f};
      f32x4 acc1 = {0.f, 0.f, 0.f, 0.f};
      const int n = nt * 16 + jl;
#pragma unroll
      for (int ks = 0; ks < 4; ks++) {
        int kb = ks * 4 + kg;
        int pos = n * H + ((kb ^ (n & 7)) << 3);
        short8 Bh = *(const short8*)(Xh + pos);
        short8 Bl = *(const short8*)(Xl + pos);
        acc0 = __builtin_amdgcn_mfma_f32_16x16x32_bf16(Ah0[ks], Bh, acc0, 0, 0, 0);
        acc0 = __builtin_amdgcn_mfma_f32_16x16x32_bf16(Al0[ks], Bh, acc0, 0, 0, 0);
        acc0 = __builtin_amdgcn_mfma_f32_16x16x32_bf16(Ah0[ks], Bl, acc0, 0, 0, 0);
        acc1 = __builtin_amdgcn_mfma_f32_16x16x32_bf16(Ah1[ks], Bh, acc1, 0, 0, 0);
        acc1 = __builtin_amdgcn_mfma_f32_16x16x32_bf16(Al1[ks], Bh, acc1, 0, 0, 0);
        acc1 = __builtin_amdgcn_mfma_f32_16x16x32_bf16(Ah1[ks], Bl, acc1, 0, 0, 0);
      }
      // D: col = lane&15, row = (lane>>4)*4 + reg  ->  Z[c][j] padded [16][132]
      {
        int jr = wv * 32 + kg * 4;
        *(f32x4*)(Zf + jl * 132 + jr)      = acc0;
        *(f32x4*)(Zf + jl * 132 + jr + 16) = acc1;
      }
      __syncthreads();
      // jet-pass for this n-tile's columns (bias + tanh-jet + re-split)
      if constexpr (JETP == 8) {
        int pl = t >> 7, j = t & (H - 1);      // 2 points x 128 neurons
        float z[JET];
#pragma unroll
        for (int q = 0; q < JET; q++) z[q] = Zf[(pl * 8 + q) * 132 + j];
        z[0] += P.bh[l * H + j];
        float o[JET];
        tanh_jet<JET>(z, o);
#pragma unroll
        for (int q = 0; q < JET; q++) {
          unsigned short hi, lo; split_bf(o[q], hi, lo);
          int pos = xpos(nt * 16 + pl * 8 + q, j);
          Xh[pos] = hi; Xl[pos] = lo;
        }
      } else {  // JETP == 16: 1 point per n-tile
        if (t < H) {
          int j = t;
          float z[JET];
#pragma unroll
          for (int q = 0; q < JET; q++) z[q] = Zf[q * 132 + j];
          z[0] += P.bh[l * H + j];
          float o[JET];
          tanh_jet<JET>(z, o);
#pragma unroll
          for (int q = 0; q < JET; q++) {
            unsigned short hi, lo; split_bf(o[q], hi, lo);
            int pos = xpos(nt * 16 + q, j);
            Xh[pos] = hi; Xl[pos] = lo;
          }
        }
      }
      __syncthreads();
    }
  }

  // ---- output layer: u[n] = sum_k Wout[k]*(hi+lo) + bo  (VALU)
  {
    int n = t >> 2, qt = t & 3;
    float s = 0.f;
#pragma unroll
    for (int b = 0; b < 4; b++) {
      int kb = qt * 4 + b;
      int pos = n * H + ((kb ^ (n & 7)) << 3);
      short8 h8 = *(const short8*)(Xh + pos);
      short8 l8 = *(const short8*)(Xl + pos);
#pragma unroll
      for (int i = 0; i < 8; i++) {
        float w = P.Wout[kb * 8 + i];
        s += w * (bf2f((unsigned short)h8[i]) + bf2f((unsigned short)l8[i]));
      }
    }
    Zf[t] = s;
  }
  __syncthreads();
  if (t < NCOL)
    U[t] = Zf[t * 4] + Zf[t * 4 + 1] + Zf[t * 4 + 2] + Zf[t * 4 + 3] + P.bo[0];
  __syncthreads();
}

// ---------------- ws layout ----------------
// floats: [0,4096) res1 | [4096,8192) res2 | [8192,8704) bnd1 |
// [8704,9216) bnd2 | [9216,18432) intf 9 terms x 1024 (term-major).
// bytes:  [73728, 270336) wt_hi | [270336, 466944) wt_lo
#define WS_RES1 0
#define WS_RES2 4096
#define WS_BND1 8192
#define WS_BND2 8704
#define WS_INTF 9216
#define WT_BYTE_OFF 73728
#define WT_COUNT (2 * 3 * H * H)   // 98304 per array

// ---------------- prep: transpose + bf16-split both nets' Wh ----------------
__global__ void __launch_bounds__(256) prep_kernel(
    const float* Wh1, const float* Wh2,
    unsigned short* wt_hi, unsigned short* wt_lo) {
  int o = blockIdx.x * 256 + threadIdx.x;   // ((net*3+l)*H + j)*H + k
  if (o >= WT_COUNT) return;
  int net = o / (3 * H * H);
  int r = o - net * 3 * H * H;
  int l = r >> 14, j = (r >> 7) & (H - 1), k = r & (H - 1);
  const float* W = (net ? Wh2 : Wh1);
  float w = W[(l * H + k) * H + j];
  unsigned short hi, lo; split_bf(w, hi, lo);
  wt_hi[o] = hi; wt_lo[o] = lo;
}

// ---------------- eval kernels ----------------
__global__ void __launch_bounds__(256, 3) residual_kernel(
    const float* xf1, const float* yf1, const float* ff1,
    const float* xf2, const float* yf2, const float* ff2,
    NetParams P1, NetParams P2,
    const unsigned short* wt_hi, const unsigned short* wt_lo, float* ws) {
  __shared__ __align__(16) unsigned short Xh[64 * H];
  __shared__ __align__(16) unsigned short Xl[64 * H];
  __shared__ __align__(16) float Zf[16 * 132];
  __shared__ float U[64];
  __shared__ float T[8];
  const int t = threadIdx.x;
  const int net = blockIdx.y;
  const float* xs = net ? xf2 : xf1;
  const float* ys = net ? yf2 : yf1;
  const float* fs = net ? ff2 : ff1;
  NetParams P = net ? P2 : P1;
  const unsigned short* wth = wt_hi + net * 3 * H * H;
  const unsigned short* wtl = wt_lo + net * 3 * H * H;
  const int base = blockIdx.x * 8;
  eval_mfma<5, 8, 8>(xs, ys, base, P, wth, wtl, Xh, Xl, Zf, U);
  if (t < 8) {
    float f = U[t * 8 + 2] + U[t * 8 + 4] - fs[base + t];  // uxx+uyy-ff
    T[t] = f * f;
  }
  __syncthreads();
  if (t == 0) {
    float s = 0.f;
#pragma unroll
    for (int i = 0; i < 8; i++) s += T[i];
    ws[(net ? WS_RES2 : WS_RES1) + blockIdx.x] = s;
  }
}

__global__ void __launch_bounds__(256, 3) boundary_kernel(
    const float* xb1, const float* yb1, const float* ub1,
    const float* xb2, const float* yb2, const float* ub2,
    NetParams P1, NetParams P2,
    const unsigned short* wt_hi, const unsigned short* wt_lo, float* ws) {
  __shared__ __align__(16) unsigned short Xh[64 * H];
  __shared__ __align__(16) unsigned short Xl[64 * H];
  __shared__ __align__(16) float Zf[16 * 132];
  __shared__ float U[64];
  __shared__ float T[8];
  const int t = threadIdx.x;
  const int net = blockIdx.y;
  const float* xs = net ? xb2 : xb1;
  const float* ys = net ? yb2 : yb1;
  const float* us = net ? ub2 : ub1;
  NetParams P = net ? P2 : P1;
  const unsigned short* wth = wt_hi + net * 3 * H * H;
  const unsigned short* wtl = wt_lo + net * 3 * H * H;
  const int base = blockIdx.x * 8;
  eval_mfma<5, 8, 8>(xs, ys, base, P, wth, wtl, Xh, Xl, Zf, U);
  if (t < 8) {
    float d = us[base + t] - U[t * 8];     // value lane
    T[t] = d * d;
  }
  __syncthreads();
  if (t == 0) {
    float s = 0.f;
#pragma unroll
    for (int i = 0; i < 8; i++) s += T[i];
    ws[(net ? WS_BND2 : WS_BND1) + blockIdx.x] = s;
  }
}

__global__ void __launch_bounds__(256, 3) interface_kernel(
    const float* xi, const float* yi, const float* fi,
    NetParams P1, NetParams P2,
    const unsigned short* wt_hi, const unsigned short* wt_lo, float* ws) {
  __shared__ __align__(16) unsigned short Xh[64 * H];
  __shared__ __align__(16) unsigned short Xl[64 * H];
  __shared__ __align__(16) float Zf[16 * 132];
  __shared__ float U1[64];
  __shared__ float U2[64];
  __shared__ float T[4 * 9];
  const int t = threadIdx.x;
  const int base = blockIdx.x * 4;
  eval_mfma<10, 16, 4>(xi, yi, base, P1, wt_hi, wt_lo, Xh, Xl, Zf, U1);
  eval_mfma<10, 16, 4>(xi, yi, base, P2, wt_hi + 3 * H * H, wt_lo + 3 * H * H,
                       Xh, Xl, Zf, U2);
  if (t < 4) {
    const float* a = U1 + t * 16;
    const float* b = U2 + t * 16;
    float fsrc = fi[base + t];
    float f1 = a[3] + a[5] - fsrc;
    float f2 = b[3] + b[5] - fsrc;
    float du = a[0] - b[0];
    float fd = f1 - f2;
    float dfl = a[2] - b[2];
    float g1x = a[6] + a[8], g1y = a[7] + a[9];
    float g2x = b[6] + b[8], g2y = b[7] + b[9];
    float dyy = a[5] - b[5];
    float dx  = a[1] - b[1];
    float dxx = a[3] - b[3];
    T[t * 9 + 0] = du * du;
    T[t * 9 + 1] = f1 * f1;
    T[t * 9 + 2] = f2 * f2;
    T[t * 9 + 3] = fd * fd;
    T[t * 9 + 4] = dfl * dfl;
    T[t * 9 + 5] = g1x * g1x + g1y * g1y + g2x * g2x + g2y * g2y;
    T[t * 9 + 6] = dyy * dyy;
    T[t * 9 + 7] = dx * dx;
    T[t * 9 + 8] = dxx * dxx;
  }
  __syncthreads();
  if (t < 9) {
    float s = 0.f;
#pragma unroll
    for (int i = 0; i < 4; i++) s += T[i * 9 + t];
    ws[WS_INTF + t * 1024 + blockIdx.x] = s;
  }
}

__global__ void __launch_bounds__(256) combine_kernel(
    const float* ws, const float* iw, float* out) {
  __shared__ float red[256];
  __shared__ float sums[13];
  const int t = threadIdx.x;
  const int off[13] = {WS_RES1, WS_RES2, WS_BND1, WS_BND2,
                       WS_INTF + 0 * 1024, WS_INTF + 1 * 1024, WS_INTF + 2 * 1024,
                       WS_INTF + 3 * 1024, WS_INTF + 4 * 1024, WS_INTF + 5 * 1024,
                       WS_INTF + 6 * 1024, WS_INTF + 7 * 1024, WS_INTF + 8 * 1024};
  const int len[13] = {4096, 4096, 512, 512,
                       1024, 1024, 1024, 1024, 1024, 1024, 1024, 1024, 1024};
  for (int r = 0; r < 13; r++) {
    float s = 0.f;
    for (int i = t; i < len[r]; i += 256) s += ws[off[r] + i];
    red[t] = s;
    __syncthreads();
    for (int w = 128; w > 0; w >>= 1) {
      if (t < w) red[t] += red[t + w];
      __syncthreads();
    }
    if (t == 0) sums[r] = red[0];
    __syncthreads();
  }
  if (t == 0) {
    const float Nf = 32768.0f, Nb = 4096.0f, Ni = 4096.0f;
    float mse_f  = (sums[0] + sums[1]) / Nf;
    float mse_ub = (sums[2] + sums[3]) / Nb;
    float su = sums[4];
    float mse_i_u    = su / Ni;
    float mse_i_uavg = su / (2.0f * Ni);
    float mse_i_res  = (sums[5] + sums[6]) / Ni;
    float mse_cont   = sums[7] / Ni;
    float mse_flux   = sums[8] / Ni;
    float mse_gres   = sums[9] / Ni;
    float mse_uyy    = sums[10] / Ni;
    float mse_ux     = sums[11] / Ni;
    float mse_uxx    = sums[12] / Ni;
    float il = iw[0] * mse_i_u + iw[1] * mse_i_uavg + iw[2] * mse_i_res
             + iw[3] * mse_cont + iw[4] * mse_flux + iw[6] * mse_gres
             + iw[5] * mse_uyy + iw[7] * mse_ux + iw[8] * mse_uxx;
    out[0] = 20.0f * mse_ub + mse_f + 5.0f * il;
  }
}

extern "C" void kernel_launch(void* const* d_in, const int* in_sizes, int n_in,
                              void* d_out, int out_size, void* d_ws, size_t ws_size,
                              hipStream_t stream) {
  const float* xb1 = (const float*)d_in[0];
  const float* yb1 = (const float*)d_in[1];
  const float* ub1 = (const float*)d_in[2];
  const float* xb2 = (const float*)d_in[3];
  const float* yb2 = (const float*)d_in[4];
  const float* ub2 = (const float*)d_in[5];
  const float* xf1 = (const float*)d_in[6];
  const float* yf1 = (const float*)d_in[7];
  const float* ff1 = (const float*)d_in[8];
  const float* xf2 = (const float*)d_in[9];
  const float* yf2 = (const float*)d_in[10];
  const float* ff2 = (const float*)d_in[11];
  const float* xi1 = (const float*)d_in[12];
  const float* yi1 = (const float*)d_in[13];
  const float* fi1 = (const float*)d_in[14];
  const float* iw  = (const float*)d_in[15];
  NetParams P1 = {(const float*)d_in[16], (const float*)d_in[17],
                  (const float*)d_in[18], (const float*)d_in[19],
                  (const float*)d_in[20], (const float*)d_in[21]};
  NetParams P2 = {(const float*)d_in[22], (const float*)d_in[23],
                  (const float*)d_in[24], (const float*)d_in[25],
                  (const float*)d_in[26], (const float*)d_in[27]};
  float* ws = (float*)d_ws;
  float* out = (float*)d_out;
  unsigned short* wt_hi = (unsigned short*)((char*)d_ws + WT_BYTE_OFF);
  unsigned short* wt_lo = wt_hi + WT_COUNT;

  hipLaunchKernelGGL(prep_kernel, dim3((WT_COUNT + 255) / 256), dim3(256), 0, stream,
                     P1.Wh, P2.Wh, wt_hi, wt_lo);
  hipLaunchKernelGGL(residual_kernel, dim3(4096, 2), dim3(256), 0, stream,
                     xf1, yf1, ff1, xf2, yf2, ff2, P1, P2, wt_hi, wt_lo, ws);
  hipLaunchKernelGGL(boundary_kernel, dim3(512, 2), dim3(256), 0, stream,
                     xb1, yb1, ub1, xb2, yb2, ub2, P1, P2, wt_hi, wt_lo, ws);
  hipLaunchKernelGGL(interface_kernel, dim3(1024), dim3(256), 0, stream,
                     xi1, yi1, fi1, P1, P2, wt_hi, wt_lo, ws);
  hipLaunchKernelGGL(combine_kernel, dim3(1), dim3(256), 0, stream,
                     ws, iw, out);
}

// Round 7
// 448.705 us; speedup vs baseline: 1.8010x; 1.0065x over previous
//
#include <hip/hip_runtime.h>

#define H 128

typedef __attribute__((ext_vector_type(4))) float f32x4;
typedef __attribute__((ext_vector_type(8))) short short8;

struct NetParams { const float *Win, *bi, *Wh, *bh, *Wout, *bo; };

// ---------------- bf16 split helpers ----------------
__device__ inline unsigned short f2bf(float f) {
  unsigned u = __float_as_uint(f);
  unsigned r = (u + 0x7FFFu + ((u >> 16) & 1u)) >> 16;   // RNE
  return (unsigned short)r;
}
__device__ inline float bf2f(unsigned short h) {
  return __uint_as_float(((unsigned)h) << 16);
}
__device__ inline void split_bf(float x, unsigned short& hi, unsigned short& lo) {
  hi = f2bf(x);
  lo = f2bf(x - bf2f(hi));
}

// ---------------- tanh jet composition (Faa di Bruno) ----------------
template<int JET>
__device__ inline void tanh_jet(const float* z, float* o) {
  float t  = tanhf(z[0]);
  float t1 = 1.0f - t * t;
  o[0] = t;
  float t2 = -2.0f * t * t1;
  if constexpr (JET == 5) {
    o[1] = t1 * z[1];
    o[2] = t2 * z[1] * z[1] + t1 * z[2];
    o[3] = t1 * z[3];
    o[4] = t2 * z[3] * z[3] + t1 * z[4];
  } else { // JET == 10
    float t3 = t1 * (6.0f * t * t - 2.0f);
    float zx = z[1], zy = z[2], zxx = z[3], zxy = z[4], zyy = z[5];
    o[1] = t1 * zx;
    o[2] = t1 * zy;
    o[3] = t2 * zx * zx + t1 * zxx;
    o[4] = t2 * zx * zy + t1 * zxy;
    o[5] = t2 * zy * zy + t1 * zyy;
    o[6] = t3 * zx * zx * zx + 3.0f * t2 * zx * zxx + t1 * z[6];
    o[7] = t3 * zx * zx * zy + t2 * (zxx * zy + 2.0f * zxy * zx) + t1 * z[7];
    o[8] = t3 * zx * zy * zy + t2 * (zyy * zx + 2.0f * zxy * zy) + t1 * z[8];
    o[9] = t3 * zy * zy * zy + 3.0f * t2 * zy * zyy + t1 * z[9];
  }
}

// X LDS layout [64 cols][128 k] ushort, XOR-swizzled at 8-ushort granularity.
__device__ inline int xpos(int n, int k) {
  return n * H + (((k >> 3) ^ (n & 7)) << 3) + (k & 7);
}

// ---------------- MFMA network jet evaluation (barrier-light) ----------------
// Block = 256 threads (4 waves), NCOL = 64 GEMM columns.
// Per layer: one dense 96-MFMA cluster (all 4 n-tiles held in 8 f32x4 regs),
// 1 barrier, then per-wave transpose via private Z region (intra-wave
// lgkmcnt only, no barrier) + jet + X write, 1 barrier. 2 barriers/layer.
template<int JET, int JETP, int NPTS>
__device__ void eval_mfma(const float* xs, const float* ys, int base,
                          const NetParams& P,
                          const unsigned short* wth, const unsigned short* wtl,
                          unsigned short* Xh, unsigned short* Xl,
                          float* Zw, float* U) {
  const int t = threadIdx.x;

  // ---- input layer: 2 -> H, jets seeded from Win directions
#pragma unroll
  for (int i = 0; i < NPTS * H / 256; i++) {
    int pair = t + i * 256;
    int p = pair >> 7, j = pair & (H - 1);
    float w0 = P.Win[j], w1 = P.Win[H + j], b = P.bi[j];
    float xp = xs[base + p], yp = ys[base + p];
    float z[JET];
#pragma unroll
    for (int q = 0; q < JET; q++) z[q] = 0.0f;
    z[0] = xp * w0 + yp * w1 + b;
    if constexpr (JET == 5) { z[1] = w0; z[3] = w1; }
    else                    { z[1] = w0; z[2] = w1; }
    float o[JET];
    tanh_jet<JET>(z, o);
#pragma unroll
    for (int q = 0; q < JET; q++) {
      unsigned short hi, lo; split_bf(o[q], hi, lo);
      int pos = xpos(p * JETP + q, j);
      Xh[pos] = hi; Xl[pos] = lo;
    }
  }
  __syncthreads();

  const int lane = t & 63, wv = t >> 6;
  const int jl = lane & 15, kg = lane >> 4;
  float* Zb = Zw + wv * (16 * 36);   // per-wave private region

  // ---- 3 hidden layers
  for (int l = 0; l < 3; l++) {
    const unsigned short* Wlh = wth + l * H * H;
    const unsigned short* Wll = wtl + l * H * H;
    short8 Ah0[4], Al0[4], Ah1[4], Al1[4];   // static-indexed
#pragma unroll
    for (int ks = 0; ks < 4; ks++) {
      int koff = ks * 32 + kg * 8;
      int j0 = wv * 32 + jl;
      Ah0[ks] = *(const short8*)(Wlh + j0 * H + koff);
      Al0[ks] = *(const short8*)(Wll + j0 * H + koff);
      Ah1[ks] = *(const short8*)(Wlh + (j0 + 16) * H + koff);
      Al1[ks] = *(const short8*)(Wll + (j0 + 16) * H + koff);
    }

    f32x4 acc[4][2];   // [nt][m-half], fully unrolled -> registers
#pragma unroll
    for (int nt = 0; nt < 4; nt++) {
      f32x4 z4 = {0.f, 0.f, 0.f, 0.f};
      acc[nt][0] = z4; acc[nt][1] = z4;
    }

    // dense MFMA cluster: 4 nt x 4 ks x 6 split-MFMAs = 96
#pragma unroll
    for (int nt = 0; nt < 4; nt++) {
      const int n = nt * 16 + jl;
#pragma unroll
      for (int ks = 0; ks < 4; ks++) {
        int kb = ks * 4 + kg;
        int pos = n * H + ((kb ^ (n & 7)) << 3);
        short8 Bh = *(const short8*)(Xh + pos);
        short8 Bl = *(const short8*)(Xl + pos);
        acc[nt][0] = __builtin_amdgcn_mfma_f32_16x16x32_bf16(Ah0[ks], Bh, acc[nt][0], 0, 0, 0);
        acc[nt][0] = __builtin_amdgcn_mfma_f32_16x16x32_bf16(Al0[ks], Bh, acc[nt][0], 0, 0, 0);
        acc[nt][0] = __builtin_amdgcn_mfma_f32_16x16x32_bf16(Ah0[ks], Bl, acc[nt][0], 0, 0, 0);
        acc[nt][1] = __builtin_amdgcn_mfma_f32_16x16x32_bf16(Ah1[ks], Bh, acc[nt][1], 0, 0, 0);
        acc[nt][1] = __builtin_amdgcn_mfma_f32_16x16x32_bf16(Al1[ks], Bh, acc[nt][1], 0, 0, 0);
        acc[nt][1] = __builtin_amdgcn_mfma_f32_16x16x32_bf16(Ah1[ks], Bl, acc[nt][1], 0, 0, 0);
      }
    }
    __syncthreads();   // all waves done READING X for this layer

    // per-wave transpose + jet + X write (no block barriers inside)
#pragma unroll
    for (int nt = 0; nt < 4; nt++) {
      // D layout: col = lane&15, row = kg*4 + reg (+16 for m-half 1)
      *(f32x4*)(Zb + jl * 36 + kg * 4)      = acc[nt][0];
      *(f32x4*)(Zb + jl * 36 + 16 + kg * 4) = acc[nt][1];
      asm volatile("s_waitcnt lgkmcnt(0)" ::: "memory");
      __builtin_amdgcn_sched_barrier(0);
      if constexpr (JETP == 8) {
        int p = lane >> 5, r = lane & 31;
        int j = wv * 32 + r;
        float z[JET];
#pragma unroll
        for (int q = 0; q < JET; q++) z[q] = Zb[(p * 8 + q) * 36 + r];
        z[0] += P.bh[l * H + j];
        float o[JET];
        tanh_jet<JET>(z, o);
#pragma unroll
        for (int q = 0; q < JET; q++) {
          unsigned short hi, lo; split_bf(o[q], hi, lo);
          int pos = xpos(nt * 16 + p * 8 + q, j);
          Xh[pos] = hi; Xl[pos] = lo;
        }
      } else {  // JETP == 16: one point per n-tile, 32 active lanes
        if (lane < 32) {
          int r = lane, j = wv * 32 + r;
          float z[JET];
#pragma unroll
          for (int q = 0; q < JET; q++) z[q] = Zb[q * 36 + r];
          z[0] += P.bh[l * H + j];
          float o[JET];
          tanh_jet<JET>(z, o);
#pragma unroll
          for (int q = 0; q < JET; q++) {
            unsigned short hi, lo; split_bf(o[q], hi, lo);
            int pos = xpos(nt * 16 + q, j);
            Xh[pos] = hi; Xl[pos] = lo;
          }
        }
      }
      // Zb reads of this nt are register-consumed before next nt's writes
      // (DS ops of one wave process in issue order; sched_barrier above
      // pins the unrolled iterations).
      asm volatile("s_waitcnt lgkmcnt(0)" ::: "memory");
      __builtin_amdgcn_sched_barrier(0);
    }
    __syncthreads();   // X(next layer) complete block-wide
  }

  // ---- output layer: u[n] = sum_k Wout[k]*(hi+lo) + bo  (VALU)
  {
    int n = t >> 2, qt = t & 3;
    float s = 0.f;
#pragma unroll
    for (int b = 0; b < 4; b++) {
      int kb = qt * 4 + b;
      int pos = n * H + ((kb ^ (n & 7)) << 3);
      short8 h8 = *(const short8*)(Xh + pos);
      short8 l8 = *(const short8*)(Xl + pos);
#pragma unroll
      for (int i = 0; i < 8; i++) {
        float w = P.Wout[kb * 8 + i];
        s += w * (bf2f((unsigned short)h8[i]) + bf2f((unsigned short)l8[i]));
      }
    }
    Zw[t] = s;   // reuse Z scratch (block-wide, after barrier below)
  }
  __syncthreads();
  if (t < 64)
    U[t] = Zw[t * 4] + Zw[t * 4 + 1] + Zw[t * 4 + 2] + Zw[t * 4 + 3] + P.bo[0];
  __syncthreads();
}

// ---------------- ws layout ----------------
// floats: [0,4096) res1 | [4096,8192) res2 | [8192,8704) bnd1 |
// [8704,9216) bnd2 | [9216,18432) intf 9 terms x 1024 (term-major).
// bytes:  [73728, 270336) wt_hi | [270336, 466944) wt_lo
#define WS_RES1 0
#define WS_RES2 4096
#define WS_BND1 8192
#define WS_BND2 8704
#define WS_INTF 9216
#define WT_BYTE_OFF 73728
#define WT_COUNT (2 * 3 * H * H)

// ---------------- prep: transpose + bf16-split both nets' Wh ----------------
__global__ void __launch_bounds__(256) prep_kernel(
    const float* Wh1, const float* Wh2,
    unsigned short* wt_hi, unsigned short* wt_lo) {
  int o = blockIdx.x * 256 + threadIdx.x;
  if (o >= WT_COUNT) return;
  int net = o / (3 * H * H);
  int r = o - net * 3 * H * H;
  int l = r >> 14, j = (r >> 7) & (H - 1), k = r & (H - 1);
  const float* W = (net ? Wh2 : Wh1);
  float w = W[(l * H + k) * H + j];
  unsigned short hi, lo; split_bf(w, hi, lo);
  wt_hi[o] = hi; wt_lo[o] = lo;
}

// ---------------- eval kernels ----------------
__global__ void __launch_bounds__(256, 3) residual_kernel(
    const float* xf1, const float* yf1, const float* ff1,
    const float* xf2, const float* yf2, const float* ff2,
    NetParams P1, NetParams P2,
    const unsigned short* wt_hi, const unsigned short* wt_lo, float* ws) {
  __shared__ __align__(16) unsigned short Xh[64 * H];
  __shared__ __align__(16) unsigned short Xl[64 * H];
  __shared__ __align__(16) float Zw[4 * 16 * 36];
  __shared__ float U[64];
  __shared__ float T[8];
  const int t = threadIdx.x;
  const int net = blockIdx.y;
  const float* xs = net ? xf2 : xf1;
  const float* ys = net ? yf2 : yf1;
  const float* fs = net ? ff2 : ff1;
  NetParams P = net ? P2 : P1;
  const unsigned short* wth = wt_hi + net * 3 * H * H;
  const unsigned short* wtl = wt_lo + net * 3 * H * H;
  const int base = blockIdx.x * 8;
  eval_mfma<5, 8, 8>(xs, ys, base, P, wth, wtl, Xh, Xl, Zw, U);
  if (t < 8) {
    float f = U[t * 8 + 2] + U[t * 8 + 4] - fs[base + t];  // uxx+uyy-ff
    T[t] = f * f;
  }
  __syncthreads();
  if (t == 0) {
    float s = 0.f;
#pragma unroll
    for (int i = 0; i < 8; i++) s += T[i];
    ws[(net ? WS_RES2 : WS_RES1) + blockIdx.x] = s;
  }
}

__global__ void __launch_bounds__(256, 3) boundary_kernel(
    const float* xb1, const float* yb1, const float* ub1,
    const float* xb2, const float* yb2, const float* ub2,
    NetParams P1, NetParams P2,
    const unsigned short* wt_hi, const unsigned short* wt_lo, float* ws) {
  __shared__ __align__(16) unsigned short Xh[64 * H];
  __shared__ __align__(16) unsigned short Xl[64 * H];
  __shared__ __align__(16) float Zw[4 * 16 * 36];
  __shared__ float U[64];
  __shared__ float T[8];
  const int t = threadIdx.x;
  const int net = blockIdx.y;
  const float* xs = net ? xb2 : xb1;
  const float* ys = net ? yb2 : yb1;
  const float* us = net ? ub2 : ub1;
  NetParams P = net ? P2 : P1;
  const unsigned short* wth = wt_hi + net * 3 * H * H;
  const unsigned short* wtl = wt_lo + net * 3 * H * H;
  const int base = blockIdx.x * 8;
  eval_mfma<5, 8, 8>(xs, ys, base, P, wth, wtl, Xh, Xl, Zw, U);
  if (t < 8) {
    float d = us[base + t] - U[t * 8];     // value lane
    T[t] = d * d;
  }
  __syncthreads();
  if (t == 0) {
    float s = 0.f;
#pragma unroll
    for (int i = 0; i < 8; i++) s += T[i];
    ws[(net ? WS_BND2 : WS_BND1) + blockIdx.x] = s;
  }
}

__global__ void __launch_bounds__(256, 3) interface_kernel(
    const float* xi, const float* yi, const float* fi,
    NetParams P1, NetParams P2,
    const unsigned short* wt_hi, const unsigned short* wt_lo, float* ws) {
  __shared__ __align__(16) unsigned short Xh[64 * H];
  __shared__ __align__(16) unsigned short Xl[64 * H];
  __shared__ __align__(16) float Zw[4 * 16 * 36];
  __shared__ float U1[64];
  __shared__ float U2[64];
  __shared__ float T[4 * 9];
  const int t = threadIdx.x;
  const int base = blockIdx.x * 4;
  eval_mfma<10, 16, 4>(xi, yi, base, P1, wt_hi, wt_lo, Xh, Xl, Zw, U1);
  eval_mfma<10, 16, 4>(xi, yi, base, P2, wt_hi + 3 * H * H, wt_lo + 3 * H * H,
                       Xh, Xl, Zw, U2);
  if (t < 4) {
    const float* a = U1 + t * 16;
    const float* b = U2 + t * 16;
    float fsrc = fi[base + t];
    float f1 = a[3] + a[5] - fsrc;
    float f2 = b[3] + b[5] - fsrc;
    float du = a[0] - b[0];
    float fd = f1 - f2;
    float dfl = a[2] - b[2];
    float g1x = a[6] + a[8], g1y = a[7] + a[9];
    float g2x = b[6] + b[8], g2y = b[7] + b[9];
    float dyy = a[5] - b[5];
    float dx  = a[1] - b[1];
    float dxx = a[3] - b[3];
    T[t * 9 + 0] = du * du;
    T[t * 9 + 1] = f1 * f1;
    T[t * 9 + 2] = f2 * f2;
    T[t * 9 + 3] = fd * fd;
    T[t * 9 + 4] = dfl * dfl;
    T[t * 9 + 5] = g1x * g1x + g1y * g1y + g2x * g2x + g2y * g2y;
    T[t * 9 + 6] = dyy * dyy;
    T[t * 9 + 7] = dx * dx;
    T[t * 9 + 8] = dxx * dxx;
  }
  __syncthreads();
  if (t < 9) {
    float s = 0.f;
#pragma unroll
    for (int i = 0; i < 4; i++) s += T[i * 9 + t];
    ws[WS_INTF + t * 1024 + blockIdx.x] = s;
  }
}

__global__ void __launch_bounds__(256) combine_kernel(
    const float* ws, const float* iw, float* out) {
  __shared__ float red[256];
  __shared__ float sums[13];
  const int t = threadIdx.x;
  const int off[13] = {WS_RES1, WS_RES2, WS_BND1, WS_BND2,
                       WS_INTF + 0 * 1024, WS_INTF + 1 * 1024, WS_INTF + 2 * 1024,
                       WS_INTF + 3 * 1024, WS_INTF + 4 * 1024, WS_INTF + 5 * 1024,
                       WS_INTF + 6 * 1024, WS_INTF + 7 * 1024, WS_INTF + 8 * 1024};
  const int len[13] = {4096, 4096, 512, 512,
                       1024, 1024, 1024, 1024, 1024, 1024, 1024, 1024, 1024};
  for (int r = 0; r < 13; r++) {
    float s = 0.f;
    for (int i = t; i < len[r]; i += 256) s += ws[off[r] + i];
    red[t] = s;
    __syncthreads();
    for (int w = 128; w > 0; w >>= 1) {
      if (t < w) red[t] += red[t + w];
      __syncthreads();
    }
    if (t == 0) sums[r] = red[0];
    __syncthreads();
  }
  if (t == 0) {
    const float Nf = 32768.0f, Nb = 4096.0f, Ni = 4096.0f;
    float mse_f  = (sums[0] + sums[1]) / Nf;
    float mse_ub = (sums[2] + sums[3]) / Nb;
    float su = sums[4];
    float mse_i_u    = su / Ni;
    float mse_i_uavg = su / (2.0f * Ni);
    float mse_i_res  = (sums[5] + sums[6]) / Ni;
    float mse_cont   = sums[7] / Ni;
    float mse_flux   = sums[8] / Ni;
    float mse_gres   = sums[9] / Ni;
    float mse_uyy    = sums[10] / Ni;
    float mse_ux     = sums[11] / Ni;
    float mse_uxx    = sums[12] / Ni;
    float il = iw[0] * mse_i_u + iw[1] * mse_i_uavg + iw[2] * mse_i_res
             + iw[3] * mse_cont + iw[4] * mse_flux + iw[6] * mse_gres
             + iw[5] * mse_uyy + iw[7] * mse_ux + iw[8] * mse_uxx;
    out[0] = 20.0f * mse_ub + mse_f + 5.0f * il;
  }
}

extern "C" void kernel_launch(void* const* d_in, const int* in_sizes, int n_in,
                              void* d_out, int out_size, void* d_ws, size_t ws_size,
                              hipStream_t stream) {
  const float* xb1 = (const float*)d_in[0];
  const float* yb1 = (const float*)d_in[1];
  const float* ub1 = (const float*)d_in[2];
  const float* xb2 = (const float*)d_in[3];
  const float* yb2 = (const float*)d_in[4];
  const float* ub2 = (const float*)d_in[5];
  const float* xf1 = (const float*)d_in[6];
  const float* yf1 = (const float*)d_in[7];
  const float* ff1 = (const float*)d_in[8];
  const float* xf2 = (const float*)d_in[9];
  const float* yf2 = (const float*)d_in[10];
  const float* ff2 = (const float*)d_in[11];
  const float* xi1 = (const float*)d_in[12];
  const float* yi1 = (const float*)d_in[13];
  const float* fi1 = (const float*)d_in[14];
  const float* iw  = (const float*)d_in[15];
  NetParams P1 = {(const float*)d_in[16], (const float*)d_in[17],
                  (const float*)d_in[18], (const float*)d_in[19],
                  (const float*)d_in[20], (const float*)d_in[21]};
  NetParams P2 = {(const float*)d_in[22], (const float*)d_in[23],
                  (const float*)d_in[24], (const float*)d_in[25],
                  (const float*)d_in[26], (const float*)d_in[27]};
  float* ws = (float*)d_ws;
  float* out = (float*)d_out;
  unsigned short* wt_hi = (unsigned short*)((char*)d_ws + WT_BYTE_OFF);
  unsigned short* wt_lo = wt_hi + WT_COUNT;

  hipLaunchKernelGGL(prep_kernel, dim3((WT_COUNT + 255) / 256), dim3(256), 0, stream,
                     P1.Wh, P2.Wh, wt_hi, wt_lo);
  hipLaunchKernelGGL(residual_kernel, dim3(4096, 2), dim3(256), 0, stream,
                     xf1, yf1, ff1, xf2, yf2, ff2, P1, P2, wt_hi, wt_lo, ws);
  hipLaunchKernelGGL(boundary_kernel, dim3(512, 2), dim3(256), 0, stream,
                     xb1, yb1, ub1, xb2, yb2, ub2, P1, P2, wt_hi, wt_lo, ws);
  hipLaunchKernelGGL(interface_kernel, dim3(1024), dim3(256), 0, stream,
                     xi1, yi1, fi1, P1, P2, wt_hi, wt_lo, ws);
  hipLaunchKernelGGL(combine_kernel, dim3(1), dim3(256), 0, stream,
                     ws, iw, out);
}

// Round 8
// 412.705 us; speedup vs baseline: 1.9581x; 1.0872x over previous
//
#include <hip/hip_runtime.h>

#define H 128

typedef __attribute__((ext_vector_type(4))) float f32x4;
typedef __attribute__((ext_vector_type(8))) short short8;

struct NetParams { const float *Win, *bi, *Wh, *bh, *Wout, *bo; };

// ---------------- bf16 helpers ----------------
__device__ inline float bf2f(unsigned short h) {
  return __uint_as_float(((unsigned)h) << 16);
}
// RNE split (prep only, one-time cost)
__device__ inline unsigned short f2bf_rne(float f) {
  unsigned u = __float_as_uint(f);
  unsigned r = (u + 0x7FFFu + ((u >> 16) & 1u)) >> 16;
  return (unsigned short)r;
}
// cheap truncation split (hot path): err <= 2^-15 rel
__device__ inline void split_bf(float x, unsigned short& hi, unsigned short& lo) {
  unsigned u = __float_as_uint(x);
  hi = (unsigned short)(u >> 16);
  float rem = x - __uint_as_float(u & 0xFFFF0000u);
  lo = (unsigned short)(__float_as_uint(rem) >> 16);
}

// fast tanh: ~8 instr, graceful +-1 at overflow, ~1e-6 rel err
__device__ inline float fast_tanhf(float x) {
  float a = fabsf(x);
  float e = __expf(2.0f * a);
  float t = 1.0f - 2.0f * __builtin_amdgcn_rcpf(e + 1.0f);
  return copysignf(t, x);
}

// ---------------- tanh jet composition (Faa di Bruno) ----------------
template<int JET>
__device__ inline void tanh_jet(const float* z, float* o) {
  float t  = fast_tanhf(z[0]);
  float t1 = 1.0f - t * t;
  o[0] = t;
  float t2 = -2.0f * t * t1;
  if constexpr (JET == 5) {
    o[1] = t1 * z[1];
    o[2] = t2 * z[1] * z[1] + t1 * z[2];
    o[3] = t1 * z[3];
    o[4] = t2 * z[3] * z[3] + t1 * z[4];
  } else { // JET == 10
    float t3 = t1 * (6.0f * t * t - 2.0f);
    float zx = z[1], zy = z[2], zxx = z[3], zxy = z[4], zyy = z[5];
    o[1] = t1 * zx;
    o[2] = t1 * zy;
    o[3] = t2 * zx * zx + t1 * zxx;
    o[4] = t2 * zx * zy + t1 * zxy;
    o[5] = t2 * zy * zy + t1 * zyy;
    o[6] = t3 * zx * zx * zx + 3.0f * t2 * zx * zxx + t1 * z[6];
    o[7] = t3 * zx * zx * zy + t2 * (zxx * zy + 2.0f * zxy * zx) + t1 * z[7];
    o[8] = t3 * zx * zy * zy + t2 * (zyy * zx + 2.0f * zxy * zy) + t1 * z[8];
    o[9] = t3 * zy * zy * zy + 3.0f * t2 * zy * zyy + t1 * z[9];
  }
}

// X LDS layout [64 cols][128 k] ushort, XOR-swizzled at 8-ushort granularity.
__device__ inline int xpos(int n, int k) {
  return n * H + (((k >> 3) ^ (n & 7)) << 3) + (k & 7);
}

// Z (transpose scratch) aliased into dead X bytes: Z[col n][row r] for wave wv
// lives at (r<16 ? Xh : Xl) + n*H + (((wv*4 + ((r>>2)&3)) ^ (n&7))<<3) + (r&3)*2.
// Per-wave byte sets are disjoint across waves; write matches f32x4 D-store.
__device__ inline float zread(const unsigned short* Xh, const unsigned short* Xl,
                              int wv, int n, int r) {
  const unsigned short* arr = (r < 16) ? Xh : Xl;
  int blk = (wv * 4 + ((r >> 2) & 3)) ^ (n & 7);
  return *(const float*)(arr + n * H + blk * 8 + (r & 3) * 2);
}

// ---------------- MFMA network jet evaluation ----------------
// Block = 256 threads (4 waves), 64 GEMM columns. LDS = Xh+Xl only (32KB) ->
// 4 blocks/CU. Z-transpose aliased into dead X region (no extra LDS).
template<int JET, int JETP, int NPTS>
__device__ void eval_mfma(const float* xs, const float* ys, int base,
                          const NetParams& P,
                          const unsigned short* wth, const unsigned short* wtl,
                          unsigned short* Xh, unsigned short* Xl, float* U) {
  const int t = threadIdx.x;
  const int lane = t & 63, wv = t >> 6;

  // ---- input layer: 2 -> H (loop-invariant weights hoisted)
  {
    int j = t & (H - 1);
    float w0 = P.Win[j], w1 = P.Win[H + j], b = P.bi[j];
#pragma unroll
    for (int i = 0; i < NPTS * H / 256; i++) {
      int p = (t + i * 256) >> 7;
      float xp = xs[base + p], yp = ys[base + p];
      float z[JET];
#pragma unroll
      for (int q = 0; q < JET; q++) z[q] = 0.0f;
      z[0] = xp * w0 + yp * w1 + b;
      if constexpr (JET == 5) { z[1] = w0; z[3] = w1; }
      else                    { z[1] = w0; z[2] = w1; }
      float o[JET];
      tanh_jet<JET>(z, o);
#pragma unroll
      for (int q = 0; q < JET; q++) {
        unsigned short hi, lo; split_bf(o[q], hi, lo);
        int pos = xpos(p * JETP + q, j);
        Xh[pos] = hi; Xl[pos] = lo;
      }
    }
  }
  __syncthreads();

  const int jl = lane & 15, kg = lane >> 4;
  const int rr = lane & 31;
  const int jj = wv * 32 + rr;
  // preload hidden biases for all 3 layers (off the jet-pass critical path)
  float bh0 = P.bh[jj], bh1 = P.bh[H + jj], bh2 = P.bh[2 * H + jj];

  // ---- 3 hidden layers
  for (int l = 0; l < 3; l++) {
    const unsigned short* Wlh = wth + l * H * H;
    const unsigned short* Wll = wtl + l * H * H;
    short8 Ah0[4], Al0[4], Ah1[4], Al1[4];
#pragma unroll
    for (int ks = 0; ks < 4; ks++) {
      int koff = ks * 32 + kg * 8;
      int j0 = wv * 32 + jl;
      Ah0[ks] = *(const short8*)(Wlh + j0 * H + koff);
      Al0[ks] = *(const short8*)(Wll + j0 * H + koff);
      Ah1[ks] = *(const short8*)(Wlh + (j0 + 16) * H + koff);
      Al1[ks] = *(const short8*)(Wll + (j0 + 16) * H + koff);
    }

    f32x4 acc[4][2];
#pragma unroll
    for (int nt = 0; nt < 4; nt++) {
      f32x4 z4 = {0.f, 0.f, 0.f, 0.f};
      acc[nt][0] = z4; acc[nt][1] = z4;
    }

    // dense MFMA cluster (96 MFMAs)
#pragma unroll
    for (int nt = 0; nt < 4; nt++) {
      const int n = nt * 16 + jl;
#pragma unroll
      for (int ks = 0; ks < 4; ks++) {
        int kb = ks * 4 + kg;
        int pos = n * H + ((kb ^ (n & 7)) << 3);
        short8 Bh = *(const short8*)(Xh + pos);
        short8 Bl = *(const short8*)(Xl + pos);
        acc[nt][0] = __builtin_amdgcn_mfma_f32_16x16x32_bf16(Ah0[ks], Bh, acc[nt][0], 0, 0, 0);
        acc[nt][0] = __builtin_amdgcn_mfma_f32_16x16x32_bf16(Al0[ks], Bh, acc[nt][0], 0, 0, 0);
        acc[nt][0] = __builtin_amdgcn_mfma_f32_16x16x32_bf16(Ah0[ks], Bl, acc[nt][0], 0, 0, 0);
        acc[nt][1] = __builtin_amdgcn_mfma_f32_16x16x32_bf16(Ah1[ks], Bh, acc[nt][1], 0, 0, 0);
        acc[nt][1] = __builtin_amdgcn_mfma_f32_16x16x32_bf16(Al1[ks], Bh, acc[nt][1], 0, 0, 0);
        acc[nt][1] = __builtin_amdgcn_mfma_f32_16x16x32_bf16(Ah1[ks], Bl, acc[nt][1], 0, 0, 0);
      }
    }
    __syncthreads();   // all waves done READING X(l); X(l) now dead

    float bhv = (l == 0) ? bh0 : ((l == 1) ? bh1 : bh2);

    // per-(nt,wave) transpose via X-aliased Z + jet + X(l+1) write
#pragma unroll
    for (int nt = 0; nt < 4; nt++) {
      const int n0 = nt * 16 + jl;
      const int zblk = ((wv * 4 + kg) ^ (n0 & 7)) << 3;
      *(f32x4*)(Xh + n0 * H + zblk) = acc[nt][0];   // rows 0..15 of wave slice
      *(f32x4*)(Xl + n0 * H + zblk) = acc[nt][1];   // rows 16..31
      asm volatile("s_waitcnt lgkmcnt(0)" ::: "memory");
      __builtin_amdgcn_sched_barrier(0);
      if constexpr (JETP == 8) {
        int p = lane >> 5;
        float z[JET];
#pragma unroll
        for (int q = 0; q < JET; q++)
          z[q] = zread(Xh, Xl, wv, nt * 16 + p * 8 + q, rr);
        asm volatile("s_waitcnt lgkmcnt(0)" ::: "memory");
        __builtin_amdgcn_sched_barrier(0);
        z[0] += bhv;
        float o[JET];
        tanh_jet<JET>(z, o);
#pragma unroll
        for (int q = 0; q < JET; q++) {
          unsigned short hi, lo; split_bf(o[q], hi, lo);
          int pos = xpos(nt * 16 + p * 8 + q, jj);
          Xh[pos] = hi; Xl[pos] = lo;
        }
      } else {  // JETP == 16
        if (lane < 32) {
          float z[JET];
#pragma unroll
          for (int q = 0; q < JET; q++)
            z[q] = zread(Xh, Xl, wv, nt * 16 + q, rr);
          asm volatile("s_waitcnt lgkmcnt(0)" ::: "memory");
          __builtin_amdgcn_sched_barrier(0);
          z[0] += bhv;
          float o[JET];
          tanh_jet<JET>(z, o);
#pragma unroll
          for (int q = 0; q < JET; q++) {
            unsigned short hi, lo; split_bf(o[q], hi, lo);
            int pos = xpos(nt * 16 + q, jj);
            Xh[pos] = hi; Xl[pos] = lo;
          }
        }
      }
    }
    __syncthreads();   // X(l+1) complete block-wide
  }

  // ---- output layer: u[n] = sum_k Wout[k]*(hi+lo) + bo
  float s;
  {
    int n = t >> 2, qt = t & 3;
    s = 0.f;
#pragma unroll
    for (int b = 0; b < 4; b++) {
      int kb = qt * 4 + b;
      int pos = n * H + ((kb ^ (n & 7)) << 3);
      short8 h8 = *(const short8*)(Xh + pos);
      short8 l8 = *(const short8*)(Xl + pos);
#pragma unroll
      for (int i = 0; i < 8; i++) {
        float w = P.Wout[kb * 8 + i];
        s += w * (bf2f((unsigned short)h8[i]) + bf2f((unsigned short)l8[i]));
      }
    }
  }
  __syncthreads();               // all X reads done; reuse Xh as f32 scratch
  float* Sc = (float*)Xh;
  Sc[t] = s;
  __syncthreads();
  if (t < 64)
    U[t] = Sc[t * 4] + Sc[t * 4 + 1] + Sc[t * 4 + 2] + Sc[t * 4 + 3] + P.bo[0];
  __syncthreads();
}

// ---------------- ws layout ----------------
#define WS_RES1 0
#define WS_RES2 4096
#define WS_BND1 8192
#define WS_BND2 8704
#define WS_INTF 9216
#define WT_BYTE_OFF 73728
#define WT_COUNT (2 * 3 * H * H)

// ---------------- prep: transpose + RNE bf16-split both nets' Wh ----------------
__global__ void __launch_bounds__(256) prep_kernel(
    const float* Wh1, const float* Wh2,
    unsigned short* wt_hi, unsigned short* wt_lo) {
  int o = blockIdx.x * 256 + threadIdx.x;
  if (o >= WT_COUNT) return;
  int net = o / (3 * H * H);
  int r = o - net * 3 * H * H;
  int l = r >> 14, j = (r >> 7) & (H - 1), k = r & (H - 1);
  const float* W = (net ? Wh2 : Wh1);
  float w = W[(l * H + k) * H + j];
  unsigned short hi = f2bf_rne(w);
  float rem = w - bf2f(hi);
  unsigned short lo = f2bf_rne(rem);
  wt_hi[o] = hi; wt_lo[o] = lo;
}

// ---------------- eval kernels ----------------
__global__ void __launch_bounds__(256, 4) residual_kernel(
    const float* xf1, const float* yf1, const float* ff1,
    const float* xf2, const float* yf2, const float* ff2,
    NetParams P1, NetParams P2,
    const unsigned short* wt_hi, const unsigned short* wt_lo, float* ws) {
  __shared__ __align__(16) unsigned short Xh[64 * H];
  __shared__ __align__(16) unsigned short Xl[64 * H];
  __shared__ float U[64];
  __shared__ float T[8];
  const int t = threadIdx.x;
  const int net = blockIdx.y;
  const float* xs = net ? xf2 : xf1;
  const float* ys = net ? yf2 : yf1;
  const float* fs = net ? ff2 : ff1;
  NetParams P = net ? P2 : P1;
  const unsigned short* wth = wt_hi + net * 3 * H * H;
  const unsigned short* wtl = wt_lo + net * 3 * H * H;
  const int base = blockIdx.x * 8;
  eval_mfma<5, 8, 8>(xs, ys, base, P, wth, wtl, Xh, Xl, U);
  if (t < 8) {
    float f = U[t * 8 + 2] + U[t * 8 + 4] - fs[base + t];  // uxx+uyy-ff
    T[t] = f * f;
  }
  __syncthreads();
  if (t == 0) {
    float s = 0.f;
#pragma unroll
    for (int i = 0; i < 8; i++) s += T[i];
    ws[(net ? WS_RES2 : WS_RES1) + blockIdx.x] = s;
  }
}

__global__ void __launch_bounds__(256, 4) boundary_kernel(
    const float* xb1, const float* yb1, const float* ub1,
    const float* xb2, const float* yb2, const float* ub2,
    NetParams P1, NetParams P2,
    const unsigned short* wt_hi, const unsigned short* wt_lo, float* ws) {
  __shared__ __align__(16) unsigned short Xh[64 * H];
  __shared__ __align__(16) unsigned short Xl[64 * H];
  __shared__ float U[64];
  __shared__ float T[8];
  const int t = threadIdx.x;
  const int net = blockIdx.y;
  const float* xs = net ? xb2 : xb1;
  const float* ys = net ? yb2 : yb1;
  const float* us = net ? ub2 : ub1;
  NetParams P = net ? P2 : P1;
  const unsigned short* wth = wt_hi + net * 3 * H * H;
  const unsigned short* wtl = wt_lo + net * 3 * H * H;
  const int base = blockIdx.x * 8;
  eval_mfma<5, 8, 8>(xs, ys, base, P, wth, wtl, Xh, Xl, U);
  if (t < 8) {
    float d = us[base + t] - U[t * 8];     // value lane
    T[t] = d * d;
  }
  __syncthreads();
  if (t == 0) {
    float s = 0.f;
#pragma unroll
    for (int i = 0; i < 8; i++) s += T[i];
    ws[(net ? WS_BND2 : WS_BND1) + blockIdx.x] = s;
  }
}

__global__ void __launch_bounds__(256, 4) interface_kernel(
    const float* xi, const float* yi, const float* fi,
    NetParams P1, NetParams P2,
    const unsigned short* wt_hi, const unsigned short* wt_lo, float* ws) {
  __shared__ __align__(16) unsigned short Xh[64 * H];
  __shared__ __align__(16) unsigned short Xl[64 * H];
  __shared__ float U1[64];
  __shared__ float U2[64];
  __shared__ float T[4 * 9];
  const int t = threadIdx.x;
  const int base = blockIdx.x * 4;
  eval_mfma<10, 16, 4>(xi, yi, base, P1, wt_hi, wt_lo, Xh, Xl, U1);
  eval_mfma<10, 16, 4>(xi, yi, base, P2, wt_hi + 3 * H * H, wt_lo + 3 * H * H,
                       Xh, Xl, U2);
  if (t < 4) {
    const float* a = U1 + t * 16;
    const float* b = U2 + t * 16;
    float fsrc = fi[base + t];
    float f1 = a[3] + a[5] - fsrc;
    float f2 = b[3] + b[5] - fsrc;
    float du = a[0] - b[0];
    float fd = f1 - f2;
    float dfl = a[2] - b[2];
    float g1x = a[6] + a[8], g1y = a[7] + a[9];
    float g2x = b[6] + b[8], g2y = b[7] + b[9];
    float dyy = a[5] - b[5];
    float dx  = a[1] - b[1];
    float dxx = a[3] - b[3];
    T[t * 9 + 0] = du * du;
    T[t * 9 + 1] = f1 * f1;
    T[t * 9 + 2] = f2 * f2;
    T[t * 9 + 3] = fd * fd;
    T[t * 9 + 4] = dfl * dfl;
    T[t * 9 + 5] = g1x * g1x + g1y * g1y + g2x * g2x + g2y * g2y;
    T[t * 9 + 6] = dyy * dyy;
    T[t * 9 + 7] = dx * dx;
    T[t * 9 + 8] = dxx * dxx;
  }
  __syncthreads();
  if (t < 9) {
    float s = 0.f;
#pragma unroll
    for (int i = 0; i < 4; i++) s += T[i * 9 + t];
    ws[WS_INTF + t * 1024 + blockIdx.x] = s;
  }
}

__global__ void __launch_bounds__(256) combine_kernel(
    const float* ws, const float* iw, float* out) {
  __shared__ float red[256];
  __shared__ float sums[13];
  const int t = threadIdx.x;
  const int off[13] = {WS_RES1, WS_RES2, WS_BND1, WS_BND2,
                       WS_INTF + 0 * 1024, WS_INTF + 1 * 1024, WS_INTF + 2 * 1024,
                       WS_INTF + 3 * 1024, WS_INTF + 4 * 1024, WS_INTF + 5 * 1024,
                       WS_INTF + 6 * 1024, WS_INTF + 7 * 1024, WS_INTF + 8 * 1024};
  const int len[13] = {4096, 4096, 512, 512,
                       1024, 1024, 1024, 1024, 1024, 1024, 1024, 1024, 1024};
  for (int r = 0; r < 13; r++) {
    float s = 0.f;
    for (int i = t; i < len[r]; i += 256) s += ws[off[r] + i];
    red[t] = s;
    __syncthreads();
    for (int w = 128; w > 0; w >>= 1) {
      if (t < w) red[t] += red[t + w];
      __syncthreads();
    }
    if (t == 0) sums[r] = red[0];
    __syncthreads();
  }
  if (t == 0) {
    const float Nf = 32768.0f, Nb = 4096.0f, Ni = 4096.0f;
    float mse_f  = (sums[0] + sums[1]) / Nf;
    float mse_ub = (sums[2] + sums[3]) / Nb;
    float su = sums[4];
    float mse_i_u    = su / Ni;
    float mse_i_uavg = su / (2.0f * Ni);
    float mse_i_res  = (sums[5] + sums[6]) / Ni;
    float mse_cont   = sums[7] / Ni;
    float mse_flux   = sums[8] / Ni;
    float mse_gres   = sums[9] / Ni;
    float mse_uyy    = sums[10] / Ni;
    float mse_ux     = sums[11] / Ni;
    float mse_uxx    = sums[12] / Ni;
    float il = iw[0] * mse_i_u + iw[1] * mse_i_uavg + iw[2] * mse_i_res
             + iw[3] * mse_cont + iw[4] * mse_flux + iw[6] * mse_gres
             + iw[5] * mse_uyy + iw[7] * mse_ux + iw[8] * mse_uxx;
    out[0] = 20.0f * mse_ub + mse_f + 5.0f * il;
  }
}

extern "C" void kernel_launch(void* const* d_in, const int* in_sizes, int n_in,
                              void* d_out, int out_size, void* d_ws, size_t ws_size,
                              hipStream_t stream) {
  const float* xb1 = (const float*)d_in[0];
  const float* yb1 = (const float*)d_in[1];
  const float* ub1 = (const float*)d_in[2];
  const float* xb2 = (const float*)d_in[3];
  const float* yb2 = (const float*)d_in[4];
  const float* ub2 = (const float*)d_in[5];
  const float* xf1 = (const float*)d_in[6];
  const float* yf1 = (const float*)d_in[7];
  const float* ff1 = (const float*)d_in[8];
  const float* xf2 = (const float*)d_in[9];
  const float* yf2 = (const float*)d_in[10];
  const float* ff2 = (const float*)d_in[11];
  const float* xi1 = (const float*)d_in[12];
  const float* yi1 = (const float*)d_in[13];
  const float* fi1 = (const float*)d_in[14];
  const float* iw  = (const float*)d_in[15];
  NetParams P1 = {(const float*)d_in[16], (const float*)d_in[17],
                  (const float*)d_in[18], (const float*)d_in[19],
                  (const float*)d_in[20], (const float*)d_in[21]};
  NetParams P2 = {(const float*)d_in[22], (const float*)d_in[23],
                  (const float*)d_in[24], (const float*)d_in[25],
                  (const float*)d_in[26], (const float*)d_in[27]};
  float* ws = (float*)d_ws;
  float* out = (float*)d_out;
  unsigned short* wt_hi = (unsigned short*)((char*)d_ws + WT_BYTE_OFF);
  unsigned short* wt_lo = wt_hi + WT_COUNT;

  hipLaunchKernelGGL(prep_kernel, dim3((WT_COUNT + 255) / 256), dim3(256), 0, stream,
                     P1.Wh, P2.Wh, wt_hi, wt_lo);
  hipLaunchKernelGGL(residual_kernel, dim3(4096, 2), dim3(256), 0, stream,
                     xf1, yf1, ff1, xf2, yf2, ff2, P1, P2, wt_hi, wt_lo, ws);
  hipLaunchKernelGGL(boundary_kernel, dim3(512, 2), dim3(256), 0, stream,
                     xb1, yb1, ub1, xb2, yb2, ub2, P1, P2, wt_hi, wt_lo, ws);
  hipLaunchKernelGGL(interface_kernel, dim3(1024), dim3(256), 0, stream,
                     xi1, yi1, fi1, P1, P2, wt_hi, wt_lo, ws);
  hipLaunchKernelGGL(combine_kernel, dim3(1), dim3(256), 0, stream,
                     ws, iw, out);
}